// Round 1
// 601.238 us; speedup vs baseline: 1.2453x; 1.2453x over previous
//
#include <hip/hip_runtime.h>

// ---------------------------------------------------------------------------
// DynamicPropertyBank fused pipeline for MI355X (gfx950).
//
// KEY SIMPLIFICATION: attn is softmax over slots normalized by its sum over
// the SINGLETON input axis -> attn == 1.0 exactly (x/x==1 for finite x>0).
// Hence upd[b,s,:] = v[b,:], Wk/Wq/g_sl are dead, gi = v@W_ih+b_ih is
// iteration-invariant, and every (b,slot) row evolves independently.
//
// prep1: repack W_hh/W1/W2/Wi/Wv/W_ih -> bf16 MFMA B-fragments in ws; zero acc.
// prep2: gi[b,0:192] for all b via MFMA (x=LN(ws@Wi+bi); v=x@Wv+bv; gi=v@W_ih).
// bank_main: 1 wave per 16 slot-rows. R1 change: 512-thread blocks (8 waves,
//   4 batches/block) so the 40 KB swgt stage is amortized over 2x work and
//   LDS/block = 81280 B -> still 2 blocks/CU but 16 waves/CU (50% occ, was 8).
//   3 fused iterations: gh GEMM (W_hh in LDS) -> GRU gates -> LN -> MLP
//   (W1 in LDS, W2 via L1) -> residual. Epilogue: slots f32 out, pv head,
//   free-slot norms -> global atomic.
// final: free_act = acc / B.
//
// ws usage: [0..31] f32 acc | f32 ofs 32: 120 frags x 512 ushort (bf16)
//           | f32 ofs 30752: gi[B*192] f32.  Needs ~12.8 MB of ws.
// ---------------------------------------------------------------------------

typedef __attribute__((ext_vector_type(4))) float f32x4;
typedef __attribute__((ext_vector_type(8))) short s16x8;

#define MFMA16 __builtin_amdgcn_mfma_f32_16x16x32_bf16

#define NB       16384
#define GIB_OFF  (32 + 120*256)   // float offset of gi buffer in ws
#define PV_N     147456           // 16384*9
#define SLOT_N   33554432         // 16384*32*64
// frag table: 0..23 Whh(ct*2+kf) | 24..39 W1 | 40..55 W2 | 56..87 Wi | 88..95 Wv | 96..119 W_ih

__device__ __forceinline__ unsigned short f2bf(float f){
  unsigned int u = __builtin_bit_cast(unsigned int, f);
  u += 0x7fffu + ((u >> 16) & 1u);               // RNE
  return (unsigned short)(u >> 16);
}
__device__ __forceinline__ float bf2f(unsigned short s){
  unsigned int u = ((unsigned int)s) << 16;
  return __builtin_bit_cast(float, u);
}
__device__ __forceinline__ float sigm(float x){
  return __builtin_amdgcn_rcpf(1.f + __expf(-x));
}
__device__ __forceinline__ float tanh_(float x){
  return 1.f - 2.f*__builtin_amdgcn_rcpf(1.f + __expf(2.f*x));
}
__device__ __forceinline__ float geluf(float x){   // tanh-form, |err| < ~3e-4 abs
  return x * sigm(1.5957691216f*x*(1.f + 0.044715f*x*x));
}

// ---------------------------------------------------------------- prep1 ----
__global__ void prep1_pack(const float* __restrict__ Wi, const float* __restrict__ Wv,
                           const float* __restrict__ Wih, const float* __restrict__ Whh,
                           const float* __restrict__ W1, const float* __restrict__ W2,
                           float* __restrict__ wsf){
  int t = blockIdx.x*256 + threadIdx.x;
  if (blockIdx.x == 0 && threadIdx.x < 32) wsf[threadIdx.x] = 0.f;  // free_act acc
  if (t >= 120*64) return;
  int frag = t >> 6, lane = t & 63;
  int q = lane >> 4, idx = lane & 15;
  const float* W; int ncols, ct, kf;
  if      (frag < 24){ W=Whh; ncols=192; ct=frag>>1;      kf=frag&1; }
  else if (frag < 40){ int f=frag-24; W=W1;  ncols=128; ct=f>>1; kf=f&1; }
  else if (frag < 56){ int f=frag-40; W=W2;  ncols=64;  ct=f>>2; kf=f&3; }
  else if (frag < 88){ int f=frag-56; W=Wi;  ncols=64;  ct=f>>3; kf=f&7; }
  else if (frag < 96){ int f=frag-88; W=Wv;  ncols=64;  ct=f>>1; kf=f&1; }
  else               { int f=frag-96; W=Wih; ncols=192; ct=f>>1; kf=f&1; }
  int k0 = kf*32 + q*8;
  int n  = ct*16 + idx;
  unsigned short* dst = (unsigned short*)(wsf + 32) + frag*512 + lane*8;
  #pragma unroll
  for (int j = 0; j < 8; ++j) dst[j] = f2bf(W[(size_t)(k0+j)*ncols + n]);
}

// ---------------------------------------------------------------- prep2 ----
__global__ __launch_bounds__(256) void prep2_gi(
    const float* __restrict__ wstate, const float* __restrict__ bi,
    const float* __restrict__ bv, const float* __restrict__ bih,
    const float* __restrict__ g_in, const float* __restrict__ b_in,
    float* __restrict__ wsf){
  __shared__ __align__(16) unsigned short sxn[4][1152];   // per-wave 16 x 72
  const f32x4 zf = {0.f,0.f,0.f,0.f};
  int tid = threadIdx.x;
  int w = __builtin_amdgcn_readfirstlane(tid >> 6);
  int lane = tid & 63, q = lane >> 4, idx = lane & 15;
  int br0 = blockIdx.x*64 + w*16;                          // 16 batch rows per wave
  const unsigned short* fb = (const unsigned short*)(wsf + 32);
  float* gib = wsf + GIB_OFF;

  // ---- x = ws @ Wi (16x256 @ 256x64) ----
  s16x8 af[8];
  #pragma unroll
  for (int kf = 0; kf < 8; ++kf){
    const float* src = wstate + (size_t)(br0+idx)*256 + kf*32 + q*8;
    f32x4 p0 = *(const f32x4*)(src);
    f32x4 p1 = *(const f32x4*)(src+4);
    s16x8 a;
    a[0]=(short)f2bf(p0[0]); a[1]=(short)f2bf(p0[1]); a[2]=(short)f2bf(p0[2]); a[3]=(short)f2bf(p0[3]);
    a[4]=(short)f2bf(p1[0]); a[5]=(short)f2bf(p1[1]); a[6]=(short)f2bf(p1[2]); a[7]=(short)f2bf(p1[3]);
    af[kf] = a;
  }
  float xv[4][4];
  #pragma unroll
  for (int ct = 0; ct < 4; ++ct){
    f32x4 acc = zf;
    #pragma unroll
    for (int kf = 0; kf < 8; ++kf)
      acc = MFMA16(af[kf], *(const s16x8*)(fb + (56 + ct*8 + kf)*512 + lane*8), acc, 0,0,0);
    float bb = bi[ct*16+idx];
    #pragma unroll
    for (int e = 0; e < 4; ++e) xv[ct][e] = acc[e] + bb;
  }
  // LN(g_in, b_in), write xn bf16 (A-layout scratch)
  #pragma unroll
  for (int e = 0; e < 4; ++e){
    float s1 = xv[0][e]+xv[1][e]+xv[2][e]+xv[3][e];
    float s2 = xv[0][e]*xv[0][e]+xv[1][e]*xv[1][e]+xv[2][e]*xv[2][e]+xv[3][e]*xv[3][e];
    #pragma unroll
    for (int m = 1; m < 16; m <<= 1){ s1 += __shfl_xor(s1,m); s2 += __shfl_xor(s2,m); }
    float mean = s1*(1.f/64.f);
    float var  = s2*(1.f/64.f) - mean*mean;
    float rs   = __builtin_amdgcn_rsqf(var + 1e-5f);
    #pragma unroll
    for (int ct = 0; ct < 4; ++ct){
      int c = ct*16+idx;
      sxn[w][(q*4+e)*72 + c] = f2bf((xv[ct][e]-mean)*rs*g_in[c] + b_in[c]);
    }
  }
  // ---- v = xn @ Wv + bv ----
  s16x8 xa0 = *(const s16x8*)(&sxn[w][idx*72 + q*8]);
  s16x8 xa1 = *(const s16x8*)(&sxn[w][idx*72 + 32 + q*8]);
  #pragma unroll
  for (int ct = 0; ct < 4; ++ct){
    f32x4 acc = MFMA16(xa0, *(const s16x8*)(fb + (88 + ct*2 + 0)*512 + lane*8), zf, 0,0,0);
    acc       = MFMA16(xa1, *(const s16x8*)(fb + (88 + ct*2 + 1)*512 + lane*8), acc, 0,0,0);
    float bb = bv[ct*16+idx];
    #pragma unroll
    for (int e = 0; e < 4; ++e) sxn[w][(q*4+e)*72 + ct*16+idx] = f2bf(acc[e] + bb);
  }
  // ---- gi = v @ W_ih + b_ih -> ws ----
  s16x8 va0 = *(const s16x8*)(&sxn[w][idx*72 + q*8]);
  s16x8 va1 = *(const s16x8*)(&sxn[w][idx*72 + 32 + q*8]);
  #pragma unroll
  for (int ct = 0; ct < 12; ++ct){
    f32x4 acc = MFMA16(va0, *(const s16x8*)(fb + (96 + ct*2 + 0)*512 + lane*8), zf, 0,0,0);
    acc       = MFMA16(va1, *(const s16x8*)(fb + (96 + ct*2 + 1)*512 + lane*8), acc, 0,0,0);
    float bb = bih[ct*16+idx];
    #pragma unroll
    for (int e = 0; e < 4; ++e)
      gib[(size_t)(br0 + q*4 + e)*192 + ct*16 + idx] = acc[e] + bb;
  }
}

// ------------------------------------------------------------- bank_main ---
// R1: 512 threads = 8 waves = 4 batches per block; LDS 81280 B -> 2 blk/CU
//     -> 16 waves/CU (was 8). Per-thread work unchanged.
__global__ __launch_bounds__(512, 4) void bank_main(
    const float* __restrict__ eps, const float* __restrict__ smu, const float* __restrict__ ssig,
    const float* __restrict__ bhh, const float* __restrict__ b1v, const float* __restrict__ b2v,
    const float* __restrict__ g_mlp, const float* __restrict__ b_mlp,
    const float* __restrict__ Wh1, const float* __restrict__ bh1,
    const float* __restrict__ Wh2, const float* __restrict__ bh2,
    float* __restrict__ wsf, float* __restrict__ out){
  __shared__ __align__(16) unsigned short swgt[20480];   // Whh frags (24) + W1 frags (16)
  __shared__ __align__(16) unsigned short sbuf[8][2176]; // per-wave 16 rows x 136 (state/h/t)
  __shared__ float sgi[4][192];
  __shared__ float sbias[512];   // [0:192) b_hh | [192:320) b1 | [320:384) b2 | [384:448) g_mlp | [448:512) b_mlp
  __shared__ float sfree[4][24];
  const f32x4 zf = {0.f,0.f,0.f,0.f};
  int tid = threadIdx.x;
  int w = __builtin_amdgcn_readfirstlane(tid >> 6);      // 0..7
  int lane = tid & 63, q = lane >> 4, idx = lane & 15;
  int pair = w >> 1, half = w & 1;                        // pair 0..3 = batch within block
  int b = blockIdx.x*4 + pair;
  const unsigned short* fb = (const unsigned short*)(wsf + 32);
  const float* gib = wsf + GIB_OFF;

  { // stage Whh + W1 fragments (40960 B) coalesced
    const uint4* src = (const uint4*)fb;
    uint4* dst = (uint4*)swgt;
    #pragma unroll
    for (int i = 0; i < 5; ++i) dst[tid + 512*i] = src[tid + 512*i];
  }
  { // bias staging: exactly 512 threads
    int i = tid;
    float vv;
    if      (i < 192) vv = bhh[i];
    else if (i < 320) vv = b1v[i-192];
    else if (i < 384) vv = b2v[i-320];
    else if (i < 448) vv = g_mlp[i-384];
    else              vv = b_mlp[i-448];
    sbias[i] = vv;
  }
  if (half == 0){
    #pragma unroll
    for (int jj = 0; jj < 3; ++jj) sgi[pair][jj*64+lane] = gib[(size_t)b*192 + jj*64 + lane];
  }
  unsigned short* S = &sbuf[w][0];
  int s0 = half*16;
  #pragma unroll
  for (int rr = 0; rr < 16; ++rr){
    int s = s0 + rr;
    float ev = eps[((size_t)b*32 + s)*64 + lane];
    S[rr*136 + lane] = f2bf(smu[s*64+lane] + ssig[s*64+lane]*ev);
  }
  __syncthreads();

  size_t obase = (size_t)PV_N + ((size_t)b*32 + s0)*64;
  #pragma unroll 1
  for (int it = 0; it < 3; ++it){
    // ---- gh = prev @ W_hh ----
    s16x8 a0 = *(const s16x8*)(&S[idx*136 + q*8]);
    s16x8 a1 = *(const s16x8*)(&S[idx*136 + 32 + q*8]);
    f32x4 gacc[12];
    #pragma unroll
    for (int ct = 0; ct < 12; ++ct){
      f32x4 acc = MFMA16(a0, *(const s16x8*)(&swgt[(ct*2+0)*512 + lane*8]), zf, 0,0,0);
      gacc[ct]  = MFMA16(a1, *(const s16x8*)(&swgt[(ct*2+1)*512 + lane*8]), acc, 0,0,0);
    }
    // ---- GRU gates ----
    float nsv[4][4];
    #pragma unroll
    for (int ct = 0; ct < 4; ++ct){
      int c = ct*16+idx;
      float bhr = sbias[c], bhz = sbias[64+c], bhn = sbias[128+c];
      float gir = sgi[pair][c], giz = sgi[pair][64+c], gin = sgi[pair][128+c];
      #pragma unroll
      for (int e = 0; e < 4; ++e){
        float r = sigm(gir + gacc[ct][e] + bhr);
        float z = sigm(giz + gacc[4+ct][e] + bhz);
        float n = tanh_(gin + r*(gacc[8+ct][e] + bhn));
        float prev = bf2f(S[(q*4+e)*136 + c]);
        nsv[ct][e] = (1.f - z)*n + z*prev;
      }
    }
    // ---- LN -> h (overwrites state cols; prev now dead, nsv in regs) ----
    #pragma unroll
    for (int e = 0; e < 4; ++e){
      float s1 = nsv[0][e]+nsv[1][e]+nsv[2][e]+nsv[3][e];
      float s2 = nsv[0][e]*nsv[0][e]+nsv[1][e]*nsv[1][e]+nsv[2][e]*nsv[2][e]+nsv[3][e]*nsv[3][e];
      #pragma unroll
      for (int m = 1; m < 16; m <<= 1){ s1 += __shfl_xor(s1,m); s2 += __shfl_xor(s2,m); }
      float mean = s1*(1.f/64.f);
      float var  = s2*(1.f/64.f) - mean*mean;
      float rs   = __builtin_amdgcn_rsqf(var + 1e-5f);
      #pragma unroll
      for (int ct = 0; ct < 4; ++ct){
        int c = ct*16+idx;
        S[(q*4+e)*136 + c] = f2bf((nsv[ct][e]-mean)*rs*sbias[384+c] + sbias[448+c]);
      }
    }
    // ---- t = gelu(h @ W1 + b1) ----
    s16x8 h0 = *(const s16x8*)(&S[idx*136 + q*8]);
    s16x8 h1 = *(const s16x8*)(&S[idx*136 + 32 + q*8]);
    f32x4 macc[8];
    #pragma unroll
    for (int ct = 0; ct < 8; ++ct){
      f32x4 acc = MFMA16(h0, *(const s16x8*)(&swgt[(24+ct*2+0)*512 + lane*8]), zf, 0,0,0);
      macc[ct]  = MFMA16(h1, *(const s16x8*)(&swgt[(24+ct*2+1)*512 + lane*8]), acc, 0,0,0);
    }
    #pragma unroll
    for (int ct = 0; ct < 8; ++ct){
      int c = ct*16+idx;
      float bb = sbias[192+c];
      #pragma unroll
      for (int e = 0; e < 4; ++e)
        S[(q*4+e)*136 + c] = f2bf(geluf(macc[ct][e] + bb));
    }
    // ---- slots = nsv + t @ W2 + b2 ----
    s16x8 t0 = *(const s16x8*)(&S[idx*136 +       q*8]);
    s16x8 t1 = *(const s16x8*)(&S[idx*136 + 32  + q*8]);
    s16x8 t2 = *(const s16x8*)(&S[idx*136 + 64  + q*8]);
    s16x8 t3 = *(const s16x8*)(&S[idx*136 + 96  + q*8]);
    #pragma unroll
    for (int ct = 0; ct < 4; ++ct){
      f32x4 acc = MFMA16(t0, *(const s16x8*)(fb + (40+ct*4+0)*512 + lane*8), zf, 0,0,0);
      acc       = MFMA16(t1, *(const s16x8*)(fb + (40+ct*4+1)*512 + lane*8), acc, 0,0,0);
      acc       = MFMA16(t2, *(const s16x8*)(fb + (40+ct*4+2)*512 + lane*8), acc, 0,0,0);
      acc       = MFMA16(t3, *(const s16x8*)(fb + (40+ct*4+3)*512 + lane*8), acc, 0,0,0);
      int c = ct*16+idx;
      float bb = sbias[320+c];
      #pragma unroll
      for (int e = 0; e < 4; ++e){
        float val = nsv[ct][e] + acc[e] + bb;
        S[(q*4+e)*136 + c] = f2bf(val);
        if (it == 2) out[obase + (size_t)(q*4+e)*64 + c] = val;   // f32-exact slots out
      }
    }
  }
  __syncthreads();

  if (half == 0){
    // pv head for this b (slots 0..8 live in this wave's S)
    int hh = lane & 31, h2 = lane >> 5;
    #pragma unroll 1
    for (int kb = 0; kb < 5; ++kb){
      int k = kb*2 + h2;
      if (k < 9){
        const float* wp = Wh1 + (size_t)k*2048 + hh;
        // 4 independent accumulators: break the 64-deep dependent FMA chain
        float a0=0.f, a1=0.f, a2=0.f, a3=0.f;
        #pragma unroll 4
        for (int dd = 0; dd < 64; dd += 4){
          a0 += bf2f(S[k*136 + dd  ]) * wp[(dd  )*32];
          a1 += bf2f(S[k*136 + dd+1]) * wp[(dd+1)*32];
          a2 += bf2f(S[k*136 + dd+2]) * wp[(dd+2)*32];
          a3 += bf2f(S[k*136 + dd+3]) * wp[(dd+3)*32];
        }
        float a = bh1[k*32 + hh] + (a0 + a1) + (a2 + a3);
        float u = geluf(a);
        float p = u * Wh2[k*32 + hh];
        #pragma unroll
        for (int m = 1; m < 32; m <<= 1) p += __shfl_xor(p, m);
        p = sigm(p + bh2[k]);
        if (hh == 0) out[(size_t)b*9 + k] = p;
      }
    }
  } else {
    // free-slot norms (slots 9..31): rows 9..15 in partner wave's buffer
    const unsigned short* SL = &sbuf[w-1][0];
    #pragma unroll 1
    for (int s = 9; s < 32; ++s){
      const unsigned short* src = (s < 16) ? (SL + s*136) : (S + (s-16)*136);
      float v = bf2f(src[lane]);
      float sq = v*v;
      #pragma unroll
      for (int m = 1; m < 64; m <<= 1) sq += __shfl_xor(sq, m);
      if (lane == 0) sfree[pair][s-9] = sqrtf(sq);
    }
  }
  __syncthreads();
  if (tid < 23) atomicAdd(&wsf[tid], sfree[0][tid] + sfree[1][tid] + sfree[2][tid] + sfree[3][tid]);
}

// ---------------------------------------------------------------- final ----
__global__ void bank_final(const float* __restrict__ wsf, float* __restrict__ out){
  int t = threadIdx.x;
  if (t < 23) out[(size_t)PV_N + SLOT_N + t] = wsf[t] * (1.f/16384.f);
}

// ---------------------------------------------------------------------------
extern "C" void kernel_launch(void* const* d_in, const int* in_sizes, int n_in,
                              void* d_out, int out_size, void* d_ws, size_t ws_size,
                              hipStream_t stream){
  (void)in_sizes; (void)n_in; (void)out_size; (void)ws_size; // needs ws >= ~12.8 MB
  const float* wstate = (const float*)d_in[0];
  const float* eps    = (const float*)d_in[1];
  const float* smu    = (const float*)d_in[2];
  const float* ssig   = (const float*)d_in[3];
  const float* Wi     = (const float*)d_in[4];
  const float* bi     = (const float*)d_in[5];
  // d_in[6..9] (Wk,bk,Wq,bq) are provably dead (attn==1)
  const float* Wv     = (const float*)d_in[10];
  const float* bv     = (const float*)d_in[11];
  const float* Wih    = (const float*)d_in[12];
  const float* bih    = (const float*)d_in[13];
  const float* Whh    = (const float*)d_in[14];
  const float* bhh    = (const float*)d_in[15];
  const float* W1     = (const float*)d_in[16];
  const float* b1     = (const float*)d_in[17];
  const float* W2     = (const float*)d_in[18];
  const float* b2     = (const float*)d_in[19];
  const float* g_in   = (const float*)d_in[20];
  const float* b_in   = (const float*)d_in[21];
  // d_in[22..23] (g_sl,b_sl) dead
  const float* g_mlp  = (const float*)d_in[24];
  const float* b_mlp  = (const float*)d_in[25];
  const float* Wh1    = (const float*)d_in[26];
  const float* bh1    = (const float*)d_in[27];
  const float* Wh2    = (const float*)d_in[28];
  const float* bh2    = (const float*)d_in[29];
  float* out = (float*)d_out;
  float* wsf = (float*)d_ws;

  prep1_pack<<<dim3(30),   dim3(256), 0, stream>>>(Wi, Wv, Wih, Whh, W1, W2, wsf);
  prep2_gi  <<<dim3(256),  dim3(256), 0, stream>>>(wstate, bi, bv, bih, g_in, b_in, wsf);
  bank_main <<<dim3(4096), dim3(512), 0, stream>>>(eps, smu, ssig, bhh, b1, b2,
                                                   g_mlp, b_mlp, Wh1, bh1, Wh2, bh2,
                                                   wsf, out);
  bank_final<<<dim3(1),    dim3(64),  0, stream>>>(wsf, out);
}